// Round 15
// baseline (2359.117 us; speedup 1.0000x reference)
//
#include <hip/hip_runtime.h>
#include <hip/hip_bf16.h>

typedef __attribute__((ext_vector_type(8))) short short8;
typedef __attribute__((ext_vector_type(4))) float f32x4;

#define SEQ 8192
#define NBATCH 4
#define NT (SEQ / 32)
#define NTH (4096 / 32)

static __device__ __forceinline__ unsigned short f2bf(float f) {
    __hip_bfloat16 h = __float2bfloat16(f);
    unsigned short u;
    __builtin_memcpy(&u, &h, 2);
    return u;
}

static __device__ __forceinline__ int4 pack8(float4 a, float4 b) {
    union { unsigned short s[8]; int4 i; } r;
    r.s[0] = f2bf(a.x); r.s[1] = f2bf(a.y); r.s[2] = f2bf(a.z); r.s[3] = f2bf(a.w);
    r.s[4] = f2bf(b.x); r.s[5] = f2bf(b.y); r.s[6] = f2bf(b.z); r.s[7] = f2bf(b.w);
    return r.i;
}

// C[M][N] = A[M][256] * W[N][256]^T (+bias)*scale.  Tile 128x128, 4 waves.
// OMODE: 0 = bf16 row-major, 1 = f32 row-major, 2 = bf16 transposed per batch
// (out[(b*256+col)*8192 + s], for V^T). (verified rounds 2-12)
template<bool A_BF16, int OMODE>
__global__ __launch_bounds__(256) void proj_gemm(
    const void* __restrict__ Ap, const float* __restrict__ W,
    const float* __restrict__ bias, void* __restrict__ Outp, float scale)
{
    __shared__ alignas(16) unsigned short As[128][40];
    __shared__ alignas(16) unsigned short Bs[128][40];

    const int tid  = threadIdx.x;
    const int lane = tid & 63;
    const int wv   = tid >> 6;
    const int wm   = (wv >> 1) * 64, wn = (wv & 1) * 64;
    const int lr   = lane & 15, lg = lane >> 4;
    const int m0   = blockIdx.x * 128;
    const int n0   = blockIdx.y * 128;

    const int srow = tid >> 1;
    const int skc  = (tid & 1) * 16;

    f32x4 acc[4][4] = {};

    for (int k0 = 0; k0 < 256; k0 += 32) {
        __syncthreads();
        if (A_BF16) {
            const unsigned short* a = (const unsigned short*)Ap + (size_t)(m0 + srow) * 256 + k0 + skc;
            int4 v0 = *(const int4*)a;
            int4 v1 = *(const int4*)(a + 8);
            *(int4*)&As[srow][skc]     = v0;
            *(int4*)&As[srow][skc + 8] = v1;
        } else {
            const float* a = (const float*)Ap + (size_t)(m0 + srow) * 256 + k0 + skc;
            const float4* a4 = (const float4*)a;
            *(int4*)&As[srow][skc]     = pack8(a4[0], a4[1]);
            *(int4*)&As[srow][skc + 8] = pack8(a4[2], a4[3]);
        }
        {
            const float* b = W + (size_t)(n0 + srow) * 256 + k0 + skc;
            const float4* b4 = (const float4*)b;
            *(int4*)&Bs[srow][skc]     = pack8(b4[0], b4[1]);
            *(int4*)&Bs[srow][skc + 8] = pack8(b4[2], b4[3]);
        }
        __syncthreads();

        short8 af[4], bfr[4];
        #pragma unroll
        for (int fm = 0; fm < 4; ++fm)
            af[fm] = *(const short8*)&As[wm + fm * 16 + lr][lg * 8];
        #pragma unroll
        for (int fn = 0; fn < 4; ++fn)
            bfr[fn] = *(const short8*)&Bs[wn + fn * 16 + lr][lg * 8];
        #pragma unroll
        for (int fm = 0; fm < 4; ++fm)
            #pragma unroll
            for (int fn = 0; fn < 4; ++fn)
                acc[fm][fn] = __builtin_amdgcn_mfma_f32_16x16x32_bf16(
                    af[fm], bfr[fn], acc[fm][fn], 0, 0, 0);
    }

    float bvals[4];
    #pragma unroll
    for (int fn = 0; fn < 4; ++fn) bvals[fn] = bias[n0 + wn + fn * 16 + lr];

    #pragma unroll
    for (int fm = 0; fm < 4; ++fm) {
        #pragma unroll
        for (int fn = 0; fn < 4; ++fn) {
            #pragma unroll
            for (int r = 0; r < 4; ++r) {
                const int row = m0 + wm + fm * 16 + lg * 4 + r;
                const int col = n0 + wn + fn * 16 + lr;
                float val = (acc[fm][fn][r] + bvals[fn]) * scale;
                if (OMODE == 1) {
                    ((float*)Outp)[(size_t)row * 256 + col] = val;
                } else if (OMODE == 0) {
                    ((unsigned short*)Outp)[(size_t)row * 256 + col] = f2bf(val);
                } else {  // V^T: [b][d=col][s]
                    const int bb = row >> 13, s = row & 8191;
                    ((unsigned short*)Outp)[((size_t)(bb * 256 + col) << 13) + s] = f2bf(val);
                }
            }
        }
    }
}

// Round 14 = round 13 kv-split with the VGPR-cap bug fixed:
// attn_partial uses __launch_bounds__(256, 1) — cap 512 VGPRs, expected ~224
// (r8 measured the identical compute structure at 224, no spill). r13's
// (256,2) capped the allocator at 128 and spilled o[8][4] to scratch
// (FETCH 1.25 GB/dispatch of scratch traffic -> 1930us). Hardware allows
// 2 blocks/CU at <=256 VGPR + 55.8KB LDS, and the 512-block grid supplies
// them, so 2 waves/SIMD occupancy comes from the grid, not launch_bounds.
__global__ __launch_bounds__(256, 1) void attn_partial(
    const unsigned short* __restrict__ Q, const unsigned short* __restrict__ K,
    const unsigned short* __restrict__ Vt, float* __restrict__ Op,
    float* __restrict__ Mp, float* __restrict__ Lp)
{
    __shared__ alignas(16) unsigned short Ks[2][32][264];
    __shared__ alignas(16) unsigned short Ps[2][8][16][40];
    __shared__ alignas(16) float Cor[2][128];
    __shared__ int Flg[2][8];

    const int tid  = threadIdx.x;
    const int lane = tid & 63;
    const int wv   = tid >> 6;
    const int lr   = lane & 15, lg = lane >> 4;
    const int b    = blockIdx.y;
    const int half = blockIdx.z;
    const int qloc = blockIdx.x * 128;
    const size_t qbase = (size_t)b * SEQ + qloc;

    // Q frags (B-operand): wave wv owns q rows wv*32..+31 (subtiles 2wv, 2wv+1)
    short8 aq0[8], aq1[8];
    #pragma unroll
    for (int c = 0; c < 8; ++c) {
        aq0[c] = *(const short8*)&Q[(qbase + wv * 32 + lr) * 256 + c * 32 + lg * 8];
        aq1[c] = *(const short8*)&Q[(qbase + wv * 32 + 16 + lr) * 256 + c * 32 + lg * 8];
    }

    float m0 = -1e30f, m1 = -1e30f;   // per-lane q = lr (log2 domain)
    f32x4 o[8][4] = {};               // [qt][dt]: rows qt*16+lg*4+r, cols wv*64+dt*16+lr
    f32x4 ol0 = {}, ol1 = {};         // l for own qt (2wv, 2wv+1), rows 4lg+r
    const short ONE = (short)0x3F80;
    const short8 vone = {ONE, ONE, ONE, ONE, ONE, ONE, ONE, ONE};

    const int krow = tid >> 3;
    const int kc8  = (tid & 7) * 8;
    const unsigned short* Kb = K + ((size_t)b * SEQ + half * 4096) * 256;
    const unsigned short* Vb = Vt + ((size_t)b * 256 << 13) + half * 4096;
    size_t vrow[4];
    #pragma unroll
    for (int dt = 0; dt < 4; ++dt)
        vrow[dt] = (size_t)(wv * 64 + dt * 16 + lr) << 13;

    {   // prologue: stage tile 0 (conflict-free 128B-interleave)
        const unsigned short* s = &Kb[(size_t)krow * 256 + kc8];
        int4 x0 = *(const int4*)(s);
        int4 x1 = *(const int4*)(s + 64);
        int4 x2 = *(const int4*)(s + 128);
        int4 x3 = *(const int4*)(s + 192);
        *(int4*)&Ks[0][krow][kc8]       = x0;
        *(int4*)&Ks[0][krow][kc8 + 64]  = x1;
        *(int4*)&Ks[0][krow][kc8 + 128] = x2;
        *(int4*)&Ks[0][krow][kc8 + 192] = x3;
    }
    __syncthreads();

    for (int t = 0; t < NTH; ++t) {
        const int p = t & 1;
        const bool have = (t + 1 < NTH);

        int4 x0, x1, x2, x3;
        if (have) {
            const unsigned short* s = &Kb[((size_t)(t + 1) * 32 + krow) * 256 + kc8];
            x0 = *(const int4*)(s);
            x1 = *(const int4*)(s + 64);
            x2 = *(const int4*)(s + 128);
            x3 = *(const int4*)(s + 192);
        }
        short8 vbr[4];
        if (t > 0) {
            const size_t kvp = (size_t)(t - 1) * 32 + lg * 8;
            #pragma unroll
            for (int dt = 0; dt < 4; ++dt)
                vbr[dt] = *(const short8*)&Vb[vrow[dt] + kvp];
        }

        // QK(t): each kb frag feeds BOTH q-subtiles (K-read economy x2)
        f32x4 s00 = {}, s01 = {}, s10 = {}, s11 = {};
        #pragma unroll
        for (int c = 0; c < 8; ++c) {
            short8 kb0 = *(const short8*)&Ks[p][lr][c * 32 + lg * 8];
            short8 kb1 = *(const short8*)&Ks[p][16 + lr][c * 32 + lg * 8];
            s00 = __builtin_amdgcn_mfma_f32_16x16x32_bf16(kb0, aq0[c], s00, 0, 0, 0);
            s01 = __builtin_amdgcn_mfma_f32_16x16x32_bf16(kb1, aq0[c], s01, 0, 0, 0);
            s10 = __builtin_amdgcn_mfma_f32_16x16x32_bf16(kb0, aq1[c], s10, 0, 0, 0);
            s11 = __builtin_amdgcn_mfma_f32_16x16x32_bf16(kb1, aq1[c], s11, 0, 0, 0);
        }

        if (have) {
            *(int4*)&Ks[p ^ 1][krow][kc8]       = x0;
            *(int4*)&Ks[p ^ 1][krow][kc8 + 64]  = x1;
            *(int4*)&Ks[p ^ 1][krow][kc8 + 128] = x2;
            *(int4*)&Ks[p ^ 1][krow][kc8 + 192] = x3;
        }

        // softmax both subtiles (log2 domain), defer-rescale THR=11
        float mx0 = fmaxf(fmaxf(fmaxf(s00[0], s00[1]), fmaxf(s00[2], s00[3])),
                          fmaxf(fmaxf(s01[0], s01[1]), fmaxf(s01[2], s01[3])));
        float mx1 = fmaxf(fmaxf(fmaxf(s10[0], s10[1]), fmaxf(s10[2], s10[3])),
                          fmaxf(fmaxf(s11[0], s11[1]), fmaxf(s11[2], s11[3])));
        mx0 = fmaxf(mx0, __shfl_xor(mx0, 16, 64));
        mx0 = fmaxf(mx0, __shfl_xor(mx0, 32, 64));
        mx1 = fmaxf(mx1, __shfl_xor(mx1, 16, 64));
        mx1 = fmaxf(mx1, __shfl_xor(mx1, 32, 64));

        const int need = __any((mx0 > m0 + 11.0f) || (mx1 > m1 + 11.0f));
        if (need) {
            float n0 = fmaxf(m0, mx0), n1 = fmaxf(m1, mx1);
            float c0 = exp2f(m0 - n0), c1 = exp2f(m1 - n1);
            m0 = n0; m1 = n1;
            if (lane < 16) {
                Cor[p ^ 1][wv * 32 + lr]      = c0;
                Cor[p ^ 1][wv * 32 + 16 + lr] = c1;
            }
        }
        if (lane == 0) { Flg[p ^ 1][2 * wv] = need; Flg[p ^ 1][2 * wv + 1] = need; }

        float pa0[4], pb0[4], pa1[4], pb1[4];
        #pragma unroll
        for (int r = 0; r < 4; ++r) {
            pa0[r] = exp2f(s00[r] - m0);
            pb0[r] = exp2f(s01[r] - m0);
            pa1[r] = exp2f(s10[r] - m1);
            pb1[r] = exp2f(s11[r] - m1);
        }

        {   // pack P -> Ps[p^1], 4x b64
            unsigned int w0 = (unsigned)f2bf(pa0[0]) | ((unsigned)f2bf(pa0[1]) << 16);
            unsigned int w1 = (unsigned)f2bf(pa0[2]) | ((unsigned)f2bf(pa0[3]) << 16);
            unsigned int w2 = (unsigned)f2bf(pb0[0]) | ((unsigned)f2bf(pb0[1]) << 16);
            unsigned int w3 = (unsigned)f2bf(pb0[2]) | ((unsigned)f2bf(pb0[3]) << 16);
            *(unsigned long long*)&Ps[p ^ 1][2 * wv][lr][4 * lg] =
                (unsigned long long)w0 | ((unsigned long long)w1 << 32);
            *(unsigned long long*)&Ps[p ^ 1][2 * wv][lr][16 + 4 * lg] =
                (unsigned long long)w2 | ((unsigned long long)w3 << 32);
            unsigned int w4 = (unsigned)f2bf(pa1[0]) | ((unsigned)f2bf(pa1[1]) << 16);
            unsigned int w5 = (unsigned)f2bf(pa1[2]) | ((unsigned)f2bf(pa1[3]) << 16);
            unsigned int w6 = (unsigned)f2bf(pb1[0]) | ((unsigned)f2bf(pb1[1]) << 16);
            unsigned int w7 = (unsigned)f2bf(pb1[2]) | ((unsigned)f2bf(pb1[3]) << 16);
            *(unsigned long long*)&Ps[p ^ 1][2 * wv + 1][lr][4 * lg] =
                (unsigned long long)w4 | ((unsigned long long)w5 << 32);
            *(unsigned long long*)&Ps[p ^ 1][2 * wv + 1][lr][16 + 4 * lg] =
                (unsigned long long)w6 | ((unsigned long long)w7 << 32);
        }

        // PV(t-1): P from Ps[p]; l via ones-column MFMA for own 2 qt only
        if (t > 0) {
            short8 pa[8];
            #pragma unroll
            for (int qt = 0; qt < 8; ++qt)
                pa[qt] = *(const short8*)&Ps[p][qt][lr][lg * 8];
            #pragma unroll
            for (int qt = 0; qt < 8; ++qt) {
                if (Flg[p][qt]) {
                    float4 c4 = *(const float4*)&Cor[p][qt * 16 + lg * 4];
                    #pragma unroll
                    for (int dt = 0; dt < 4; ++dt) {
                        o[qt][dt][0] *= c4.x; o[qt][dt][1] *= c4.y;
                        o[qt][dt][2] *= c4.z; o[qt][dt][3] *= c4.w;
                    }
                    if (qt == 2 * wv) {
                        ol0[0] *= c4.x; ol0[1] *= c4.y; ol0[2] *= c4.z; ol0[3] *= c4.w;
                    }
                    if (qt == 2 * wv + 1) {
                        ol1[0] *= c4.x; ol1[1] *= c4.y; ol1[2] *= c4.z; ol1[3] *= c4.w;
                    }
                }
                #pragma unroll
                for (int dt = 0; dt < 4; ++dt)
                    o[qt][dt] = __builtin_amdgcn_mfma_f32_16x16x32_bf16(pa[qt], vbr[dt], o[qt][dt], 0, 0, 0);
            }
            ol0 = __builtin_amdgcn_mfma_f32_16x16x32_bf16(pa[2 * wv], vone, ol0, 0, 0, 0);
            ol1 = __builtin_amdgcn_mfma_f32_16x16x32_bf16(pa[2 * wv + 1], vone, ol1, 0, 0, 0);
        }
        __syncthreads();
    }

    // epilogue: PV(NTH-1) from Ps[NTH&1]
    {
        const int p = NTH & 1;
        const size_t kvp = (size_t)(NTH - 1) * 32 + lg * 8;
        short8 vbr[4];
        #pragma unroll
        for (int dt = 0; dt < 4; ++dt)
            vbr[dt] = *(const short8*)&Vb[vrow[dt] + kvp];
        short8 pa[8];
        #pragma unroll
        for (int qt = 0; qt < 8; ++qt)
            pa[qt] = *(const short8*)&Ps[p][qt][lr][lg * 8];
        #pragma unroll
        for (int qt = 0; qt < 8; ++qt) {
            if (Flg[p][qt]) {
                float4 c4 = *(const float4*)&Cor[p][qt * 16 + lg * 4];
                #pragma unroll
                for (int dt = 0; dt < 4; ++dt) {
                    o[qt][dt][0] *= c4.x; o[qt][dt][1] *= c4.y;
                    o[qt][dt][2] *= c4.z; o[qt][dt][3] *= c4.w;
                }
                if (qt == 2 * wv) {
                    ol0[0] *= c4.x; ol0[1] *= c4.y; ol0[2] *= c4.z; ol0[3] *= c4.w;
                }
                if (qt == 2 * wv + 1) {
                    ol1[0] *= c4.x; ol1[1] *= c4.y; ol1[2] *= c4.z; ol1[3] *= c4.w;
                }
            }
            #pragma unroll
            for (int dt = 0; dt < 4; ++dt)
                o[qt][dt] = __builtin_amdgcn_mfma_f32_16x16x32_bf16(pa[qt], vbr[dt], o[qt][dt], 0, 0, 0);
        }
        ol0 = __builtin_amdgcn_mfma_f32_16x16x32_bf16(pa[2 * wv], vone, ol0, 0, 0, 0);
        ol1 = __builtin_amdgcn_mfma_f32_16x16x32_bf16(pa[2 * wv + 1], vone, ol1, 0, 0, 0);
    }

    // write unnormalized partials + m + l
    const size_t obase = ((size_t)(half * NBATCH + b) * SEQ + qloc);
    #pragma unroll
    for (int qt = 0; qt < 8; ++qt)
        #pragma unroll
        for (int dt = 0; dt < 4; ++dt)
            #pragma unroll
            for (int r = 0; r < 4; ++r)
                Op[(obase + qt * 16 + lg * 4 + r) * 256 + wv * 64 + dt * 16 + lr] = o[qt][dt][r];
    if (lane < 16) {
        Mp[obase + wv * 32 + lr]      = m0;
        Mp[obase + wv * 32 + 16 + lr] = m1;
    }
    if (lr == 0) {
        #pragma unroll
        for (int r = 0; r < 4; ++r) {
            Lp[obase + (2 * wv) * 16 + 4 * lg + r]     = ol0[r];
            Lp[obase + (2 * wv + 1) * 16 + 4 * lg + r] = ol1[r];
        }
    }
}

// Combine the two kv-half partials: O = (O1*2^(m1-m) + O2*2^(m2-m)) / l.
__global__ __launch_bounds__(256) void combine_kernel(
    const float* __restrict__ Op, const float* __restrict__ Mp,
    const float* __restrict__ Lp, unsigned short* __restrict__ ab)
{
    const int gid = blockIdx.x * 256 + threadIdx.x;
    const int row = gid >> 5;
    const int c8  = (gid & 31) * 8;
    const size_t NR = (size_t)NBATCH * SEQ;

    float m1 = Mp[row], m2 = Mp[NR + row];
    float l1 = Lp[row], l2 = Lp[NR + row];
    float m  = fmaxf(m1, m2);
    float a1 = exp2f(m1 - m), a2 = exp2f(m2 - m);
    float invl = 1.f / (l1 * a1 + l2 * a2);

    const float4* o1 = (const float4*)&Op[(size_t)row * 256 + c8];
    const float4* o2 = (const float4*)&Op[(NR + (size_t)row) * 256 + c8];
    float4 x1 = o1[0], y1 = o1[1];
    float4 x2 = o2[0], y2 = o2[1];

    union { unsigned short s[8]; int4 i; } r;
    r.s[0] = f2bf((x1.x * a1 + x2.x * a2) * invl);
    r.s[1] = f2bf((x1.y * a1 + x2.y * a2) * invl);
    r.s[2] = f2bf((x1.z * a1 + x2.z * a2) * invl);
    r.s[3] = f2bf((x1.w * a1 + x2.w * a2) * invl);
    r.s[4] = f2bf((y1.x * a1 + y2.x * a2) * invl);
    r.s[5] = f2bf((y1.y * a1 + y2.y * a2) * invl);
    r.s[6] = f2bf((y1.z * a1 + y2.z * a2) * invl);
    r.s[7] = f2bf((y1.w * a1 + y2.w * a2) * invl);
    *(int4*)&ab[(size_t)row * 256 + c8] = r.i;
}

// Fallback (r12, verified 428us): used when ws_size is too small for partials.
__global__ __launch_bounds__(256, 2) void attn_kernel(
    const unsigned short* __restrict__ Q, const unsigned short* __restrict__ K,
    const unsigned short* __restrict__ Vt, unsigned short* __restrict__ A)
{
    __shared__ alignas(16) unsigned short Ks[2][32][264];
    __shared__ alignas(16) unsigned short Ps[2][4][16][40];
    __shared__ alignas(16) float Cor[2][4][16];
    __shared__ int Flg[2][4];

    const int tid  = threadIdx.x;
    const int lane = tid & 63;
    const int wv   = tid >> 6;
    const int lr   = lane & 15, lg = lane >> 4;
    const int b    = blockIdx.y;
    const size_t qblk = (size_t)b * SEQ + blockIdx.x * 64;

    short8 aq[8];
    #pragma unroll
    for (int c = 0; c < 8; ++c)
        aq[c] = *(const short8*)&Q[(qblk + wv * 16 + lr) * 256 + c * 32 + lg * 8];

    float m_run = -1e30f;
    f32x4 o[4][4] = {};
    f32x4 o_l[4] = {};
    const short ONE = (short)0x3F80;
    const short8 vone = {ONE, ONE, ONE, ONE, ONE, ONE, ONE, ONE};

    const int krow = tid >> 3;
    const int kc8  = (tid & 7) * 8;
    const unsigned short* Kb = K + (size_t)b * SEQ * 256;
    const unsigned short* Vb = Vt + ((size_t)b * 256 << 13);
    size_t vrow[4];
    #pragma unroll
    for (int dt = 0; dt < 4; ++dt)
        vrow[dt] = (size_t)(wv * 64 + dt * 16 + lr) << 13;

    {
        const unsigned short* s = &Kb[(size_t)krow * 256 + kc8];
        int4 x0 = *(const int4*)(s);
        int4 x1 = *(const int4*)(s + 64);
        int4 x2 = *(const int4*)(s + 128);
        int4 x3 = *(const int4*)(s + 192);
        *(int4*)&Ks[0][krow][kc8]       = x0;
        *(int4*)&Ks[0][krow][kc8 + 64]  = x1;
        *(int4*)&Ks[0][krow][kc8 + 128] = x2;
        *(int4*)&Ks[0][krow][kc8 + 192] = x3;
    }
    __syncthreads();

    for (int t = 0; t < NT; ++t) {
        const int p = t & 1;
        const bool have = (t + 1 < NT);

        int4 x0, x1, x2, x3;
        if (have) {
            const unsigned short* s = &Kb[((size_t)(t + 1) * 32 + krow) * 256 + kc8];
            x0 = *(const int4*)(s);
            x1 = *(const int4*)(s + 64);
            x2 = *(const int4*)(s + 128);
            x3 = *(const int4*)(s + 192);
        }
        short8 vbr[4];
        if (t > 0) {
            const size_t kvp = (size_t)(t - 1) * 32 + lg * 8;
            #pragma unroll
            for (int dt = 0; dt < 4; ++dt)
                vbr[dt] = *(const short8*)&Vb[vrow[dt] + kvp];
        }

        f32x4 s0 = {}, s1 = {};
        #pragma unroll
        for (int c = 0; c < 8; ++c) {
            short8 kb0 = *(const short8*)&Ks[p][lr][c * 32 + lg * 8];
            short8 kb1 = *(const short8*)&Ks[p][16 + lr][c * 32 + lg * 8];
            s0 = __builtin_amdgcn_mfma_f32_16x16x32_bf16(kb0, aq[c], s0, 0, 0, 0);
            s1 = __builtin_amdgcn_mfma_f32_16x16x32_bf16(kb1, aq[c], s1, 0, 0, 0);
        }

        if (have) {
            *(int4*)&Ks[p ^ 1][krow][kc8]       = x0;
            *(int4*)&Ks[p ^ 1][krow][kc8 + 64]  = x1;
            *(int4*)&Ks[p ^ 1][krow][kc8 + 128] = x2;
            *(int4*)&Ks[p ^ 1][krow][kc8 + 192] = x3;
        }

        float mx = fmaxf(fmaxf(fmaxf(s0[0], s0[1]), fmaxf(s0[2], s0[3])),
                         fmaxf(fmaxf(s1[0], s1[1]), fmaxf(s1[2], s1[3])));
        mx = fmaxf(mx, __shfl_xor(mx, 16, 64));
        mx = fmaxf(mx, __shfl_xor(mx, 32, 64));

        const int need = __any(mx > m_run + 11.0f);
        if (need) {
            float mnew = fmaxf(m_run, mx);
            float corr = exp2f(m_run - mnew);
            m_run = mnew;
            if (lane < 16) Cor[p ^ 1][wv][lr] = corr;
        }
        if (lane == 0) Flg[p ^ 1][wv] = need;

        float p0[4], p1[4];
        #pragma unroll
        for (int r = 0; r < 4; ++r) {
            p0[r] = exp2f(s0[r] - m_run);
            p1[r] = exp2f(s1[r] - m_run);
        }

        {
            unsigned int w0 = (unsigned)f2bf(p0[0]) | ((unsigned)f2bf(p0[1]) << 16);
            unsigned int w1 = (unsigned)f2bf(p0[2]) | ((unsigned)f2bf(p0[3]) << 16);
            unsigned int w2 = (unsigned)f2bf(p1[0]) | ((unsigned)f2bf(p1[1]) << 16);
            unsigned int w3 = (unsigned)f2bf(p1[2]) | ((unsigned)f2bf(p1[3]) << 16);
            *(unsigned long long*)&Ps[p ^ 1][wv][lr][4 * lg] =
                (unsigned long long)w0 | ((unsigned long long)w1 << 32);
            *(unsigned long long*)&Ps[p ^ 1][wv][lr][16 + 4 * lg] =
                (unsigned long long)w2 | ((unsigned long long)w3 << 32);
        }

        if (t > 0) {
            short8 pa[4];
            #pragma unroll
            for (int qt = 0; qt < 4; ++qt)
                pa[qt] = *(const short8*)&Ps[p][qt][lr][lg * 8];
            #pragma unroll
            for (int qt = 0; qt < 4; ++qt) {
                if (Flg[p][qt]) {
                    float4 c4 = *(const float4*)&Cor[p][qt][lg * 4];
                    #pragma unroll
                    for (int dt = 0; dt < 4; ++dt) {
                        o[qt][dt][0] *= c4.x; o[qt][dt][1] *= c4.y;
                        o[qt][dt][2] *= c4.z; o[qt][dt][3] *= c4.w;
                    }
                    o_l[qt][0] *= c4.x; o_l[qt][1] *= c4.y;
                    o_l[qt][2] *= c4.z; o_l[qt][3] *= c4.w;
                }
                #pragma unroll
                for (int dt = 0; dt < 4; ++dt)
                    o[qt][dt] = __builtin_amdgcn_mfma_f32_16x16x32_bf16(pa[qt], vbr[dt], o[qt][dt], 0, 0, 0);
                o_l[qt] = __builtin_amdgcn_mfma_f32_16x16x32_bf16(pa[qt], vone, o_l[qt], 0, 0, 0);
            }
        }
        __syncthreads();
    }

    {
        const int p = NT & 1;
        const size_t kvp = (size_t)(NT - 1) * 32 + lg * 8;
        short8 vbr[4];
        #pragma unroll
        for (int dt = 0; dt < 4; ++dt)
            vbr[dt] = *(const short8*)&Vb[vrow[dt] + kvp];
        short8 pa[4];
        #pragma unroll
        for (int qt = 0; qt < 4; ++qt)
            pa[qt] = *(const short8*)&Ps[p][qt][lr][lg * 8];
        #pragma unroll
        for (int qt = 0; qt < 4; ++qt) {
            if (Flg[p][qt]) {
                float4 c4 = *(const float4*)&Cor[p][qt][lg * 4];
                #pragma unroll
                for (int dt = 0; dt < 4; ++dt) {
                    o[qt][dt][0] *= c4.x; o[qt][dt][1] *= c4.y;
                    o[qt][dt][2] *= c4.z; o[qt][dt][3] *= c4.w;
                }
                o_l[qt][0] *= c4.x; o_l[qt][1] *= c4.y;
                o_l[qt][2] *= c4.z; o_l[qt][3] *= c4.w;
            }
            #pragma unroll
            for (int dt = 0; dt < 4; ++dt)
                o[qt][dt] = __builtin_amdgcn_mfma_f32_16x16x32_bf16(pa[qt], vbr[dt], o[qt][dt], 0, 0, 0);
            o_l[qt] = __builtin_amdgcn_mfma_f32_16x16x32_bf16(pa[qt], vone, o_l[qt], 0, 0, 0);
        }
    }

    #pragma unroll
    for (int qt = 0; qt < 4; ++qt) {
        float inv[4] = {1.f / o_l[qt][0], 1.f / o_l[qt][1],
                        1.f / o_l[qt][2], 1.f / o_l[qt][3]};
        #pragma unroll
        for (int dt = 0; dt < 4; ++dt)
            #pragma unroll
            for (int r = 0; r < 4; ++r)
                A[(qblk + qt * 16 + lg * 4 + r) * 256 + wv * 64 + dt * 16 + lr] =
                    f2bf(o[qt][dt][r] * inv[r]);
    }
}

extern "C" void kernel_launch(void* const* d_in, const int* in_sizes, int n_in,
                              void* d_out, int out_size, void* d_ws, size_t ws_size,
                              hipStream_t stream) {
    (void)in_sizes; (void)n_in; (void)out_size;
    const float* x  = (const float*)d_in[0];
    const float* Wq = (const float*)d_in[1];
    const float* bq = (const float*)d_in[2];
    const float* Wk = (const float*)d_in[3];
    const float* bk = (const float*)d_in[4];
    const float* Wv = (const float*)d_in[5];
    const float* bv = (const float*)d_in[6];
    const float* Wo = (const float*)d_in[7];
    const float* bo = (const float*)d_in[8];
    float* out = (float*)d_out;

    char* ws = (char*)d_ws;
    const size_t MB = (size_t)1024 * 1024;
    unsigned short* qb = (unsigned short*)(ws);
    unsigned short* kb = (unsigned short*)(ws + 16 * MB);
    unsigned short* vt = (unsigned short*)(ws + 32 * MB);  // V^T [b][d][S]

    const size_t NEED = 113 * MB;  // 48 qkv + 64 Opart + 0.5 M/L
    dim3 gg(256, 2), bb(256);
    proj_gemm<false, 0><<<gg, bb, 0, stream>>>(x, Wq, bq, qb, 0.0625f * 1.44269504f);
    proj_gemm<false, 0><<<gg, bb, 0, stream>>>(x, Wk, bk, kb, 1.0f);
    proj_gemm<false, 2><<<gg, bb, 0, stream>>>(x, Wv, bv, vt, 1.0f);

    if (ws_size >= NEED) {
        float* Op = (float*)(ws + 48 * MB);            // 64 MB (2 halves)
        float* Mp = (float*)(ws + 112 * MB);           // 256 KB
        float* Lp = (float*)(ws + 112 * MB + 256 * 1024);
        unsigned short* ab = kb;                       // kb dead after attn
        attn_partial<<<dim3(64, NBATCH, 2), bb, 0, stream>>>(qb, kb, vt, Op, Mp, Lp);
        combine_kernel<<<dim3(4096), bb, 0, stream>>>(Op, Mp, Lp, ab);
        proj_gemm<true, 1><<<gg, bb, 0, stream>>>(ab, Wo, bo, out, 1.0f);
    } else {
        unsigned short* ab = (unsigned short*)(ws + 48 * MB);
        attn_kernel<<<dim3(128, NBATCH), bb, 0, stream>>>(qb, kb, vt, ab);
        proj_gemm<true, 1><<<gg, bb, 0, stream>>>(ab, Wo, bo, out, 1.0f);
    }
}

// Round 16
// 428.351 us; speedup vs baseline: 5.5074x; 5.5074x over previous
//
#include <hip/hip_runtime.h>
#include <hip/hip_bf16.h>

typedef __attribute__((ext_vector_type(8))) short short8;
typedef __attribute__((ext_vector_type(4))) float f32x4;

#define SEQ 8192
#define NBATCH 4
#define NT (SEQ / 32)

static __device__ __forceinline__ unsigned short f2bf(float f) {
    __hip_bfloat16 h = __float2bfloat16(f);
    unsigned short u;
    __builtin_memcpy(&u, &h, 2);
    return u;
}

static __device__ __forceinline__ int4 pack8(float4 a, float4 b) {
    union { unsigned short s[8]; int4 i; } r;
    r.s[0] = f2bf(a.x); r.s[1] = f2bf(a.y); r.s[2] = f2bf(a.z); r.s[3] = f2bf(a.w);
    r.s[4] = f2bf(b.x); r.s[5] = f2bf(b.y); r.s[6] = f2bf(b.z); r.s[7] = f2bf(b.w);
    return r.i;
}

// C[M][N] = A[M][256] * W[N][256]^T (+bias)*scale.  Tile 128x128, 4 waves.
// OMODE: 0 = bf16 row-major, 1 = f32 row-major, 2 = bf16 transposed per batch
// (out[(b*256+col)*8192 + s], for V^T). (verified rounds 2-12)
template<bool A_BF16, int OMODE>
__global__ __launch_bounds__(256) void proj_gemm(
    const void* __restrict__ Ap, const float* __restrict__ W,
    const float* __restrict__ bias, void* __restrict__ Outp, float scale)
{
    __shared__ alignas(16) unsigned short As[128][40];
    __shared__ alignas(16) unsigned short Bs[128][40];

    const int tid  = threadIdx.x;
    const int lane = tid & 63;
    const int wv   = tid >> 6;
    const int wm   = (wv >> 1) * 64, wn = (wv & 1) * 64;
    const int lr   = lane & 15, lg = lane >> 4;
    const int m0   = blockIdx.x * 128;
    const int n0   = blockIdx.y * 128;

    const int srow = tid >> 1;
    const int skc  = (tid & 1) * 16;

    f32x4 acc[4][4] = {};

    for (int k0 = 0; k0 < 256; k0 += 32) {
        __syncthreads();
        if (A_BF16) {
            const unsigned short* a = (const unsigned short*)Ap + (size_t)(m0 + srow) * 256 + k0 + skc;
            int4 v0 = *(const int4*)a;
            int4 v1 = *(const int4*)(a + 8);
            *(int4*)&As[srow][skc]     = v0;
            *(int4*)&As[srow][skc + 8] = v1;
        } else {
            const float* a = (const float*)Ap + (size_t)(m0 + srow) * 256 + k0 + skc;
            const float4* a4 = (const float4*)a;
            *(int4*)&As[srow][skc]     = pack8(a4[0], a4[1]);
            *(int4*)&As[srow][skc + 8] = pack8(a4[2], a4[3]);
        }
        {
            const float* b = W + (size_t)(n0 + srow) * 256 + k0 + skc;
            const float4* b4 = (const float4*)b;
            *(int4*)&Bs[srow][skc]     = pack8(b4[0], b4[1]);
            *(int4*)&Bs[srow][skc + 8] = pack8(b4[2], b4[3]);
        }
        __syncthreads();

        short8 af[4], bfr[4];
        #pragma unroll
        for (int fm = 0; fm < 4; ++fm)
            af[fm] = *(const short8*)&As[wm + fm * 16 + lr][lg * 8];
        #pragma unroll
        for (int fn = 0; fn < 4; ++fn)
            bfr[fn] = *(const short8*)&Bs[wn + fn * 16 + lr][lg * 8];
        #pragma unroll
        for (int fm = 0; fm < 4; ++fm)
            #pragma unroll
            for (int fn = 0; fn < 4; ++fn)
                acc[fm][fn] = __builtin_amdgcn_mfma_f32_16x16x32_bf16(
                    af[fm], bfr[fn], acc[fm][fn], 0, 0, 0);
    }

    float bvals[4];
    #pragma unroll
    for (int fn = 0; fn < 4; ++fn) bvals[fn] = bias[n0 + wn + fn * 16 + lr];

    #pragma unroll
    for (int fm = 0; fm < 4; ++fm) {
        #pragma unroll
        for (int fn = 0; fn < 4; ++fn) {
            #pragma unroll
            for (int r = 0; r < 4; ++r) {
                const int row = m0 + wm + fm * 16 + lg * 4 + r;
                const int col = n0 + wn + fn * 16 + lr;
                float val = (acc[fm][fn][r] + bvals[fn]) * scale;
                if (OMODE == 1) {
                    ((float*)Outp)[(size_t)row * 256 + col] = val;
                } else if (OMODE == 0) {
                    ((unsigned short*)Outp)[(size_t)row * 256 + col] = f2bf(val);
                } else {  // V^T: [b][d=col][s]
                    const int bb = row >> 13, s = row & 8191;
                    ((unsigned short*)Outp)[((size_t)(bb * 256 + col) << 13) + s] = f2bf(val);
                }
            }
        }
    }
}

// Flash attention, round 16 = round 12 (best verified: 428us, VGPR 100)
// + bijective XCD swizzle (T1): flatten grid to 512 blocks; swz =
// (id%8)*64 + id/8 gives each XCD 64 contiguous q-blocks of ONE batch so
// its 4MB L2 caches that batch's K/V^T instead of thrashing across 4
// batches (FETCH 139MB ~= 3x compulsory). Pure block remap — math,
// registers, and schedule identical to r12.
// Verified r12 components: ones-column l in MFMA accumulator, conflict-free
// 128B-interleaved K staging, swapped QK (D[kv][q]), per-lane log2 softmax,
// defer-rescale THR=11, Ps/Cor/Flg dbuf, PV lags 1 iter, V^T direct from
// global, one barrier/iter, __launch_bounds__(256,2).
__global__ __launch_bounds__(256, 2) void attn_kernel(
    const unsigned short* __restrict__ Q, const unsigned short* __restrict__ K,
    const unsigned short* __restrict__ Vt, unsigned short* __restrict__ A)
{
    __shared__ alignas(16) unsigned short Ks[2][32][264];   // [buf][kv][d], pad +8
    __shared__ alignas(16) unsigned short Ps[2][4][16][40]; // [buf][qt][q][kv]
    __shared__ alignas(16) float Cor[2][4][16];
    __shared__ int Flg[2][4];

    const int tid  = threadIdx.x;
    const int lane = tid & 63;
    const int wv   = tid >> 6;
    const int lr   = lane & 15, lg = lane >> 4;

    // XCD swizzle: 512 blocks, 8 XCDs, 64 blocks/XCD, round-robin dispatch.
    const int swz = (blockIdx.x & 7) * 64 + (blockIdx.x >> 3);
    const int b   = swz >> 7;          // batch
    const int qx  = swz & 127;         // q-block within batch
    const size_t qblk = (size_t)b * SEQ + qx * 64;

    // Q frags (B-operand): wave wv owns q-tile wv
    short8 aq[8];
    #pragma unroll
    for (int c = 0; c < 8; ++c)
        aq[c] = *(const short8*)&Q[(qblk + wv * 16 + lr) * 256 + c * 32 + lg * 8];

    float m_run = -1e30f;   // per-lane: q-row = lr (log2 domain)
    f32x4 o[4][4] = {};     // [qt][dt]: rows qt*16+lg*4+r, cols wv*64+dt*16+lr
    f32x4 o_l[4] = {};      // [qt]: l (sum of P) for rows qt*16+lg*4+r
    const short ONE = (short)0x3F80;   // bf16 1.0
    const short8 vone = {ONE, ONE, ONE, ONE, ONE, ONE, ONE, ONE};

    const int krow = tid >> 3;           // K staging: row 0..31
    const int kc8  = (tid & 7) * 8;      // chunk element offset (16B chunks)
    const unsigned short* Kb = K + (size_t)b * SEQ * 256;
    const unsigned short* Vb = Vt + ((size_t)b * 256 << 13);
    size_t vrow[4];
    #pragma unroll
    for (int dt = 0; dt < 4; ++dt)
        vrow[dt] = (size_t)(wv * 64 + dt * 16 + lr) << 13;

    // prologue: stage tile 0 into Ks[0] (128B-interleaved chunks)
    {
        const unsigned short* s = &Kb[(size_t)krow * 256 + kc8];
        int4 x0 = *(const int4*)(s);
        int4 x1 = *(const int4*)(s + 64);
        int4 x2 = *(const int4*)(s + 128);
        int4 x3 = *(const int4*)(s + 192);
        *(int4*)&Ks[0][krow][kc8]       = x0;
        *(int4*)&Ks[0][krow][kc8 + 64]  = x1;
        *(int4*)&Ks[0][krow][kc8 + 128] = x2;
        *(int4*)&Ks[0][krow][kc8 + 192] = x3;
    }
    __syncthreads();

    for (int t = 0; t < NT; ++t) {
        const int p = t & 1;
        const bool have = (t + 1 < NT);

        // issue K(t+1) loads early (latency hides under QK)
        int4 x0, x1, x2, x3;
        if (have) {
            const unsigned short* s = &Kb[((size_t)(t + 1) * 32 + krow) * 256 + kc8];
            x0 = *(const int4*)(s);
            x1 = *(const int4*)(s + 64);
            x2 = *(const int4*)(s + 128);
            x3 = *(const int4*)(s + 192);
        }
        // V^T frags for PV(t-1), direct from global (L2-resident)
        short8 vbr[4];
        if (t > 0) {
            const size_t kvp = (size_t)(t - 1) * 32 + lg * 8;
            #pragma unroll
            for (int dt = 0; dt < 4; ++dt)
                vbr[dt] = *(const short8*)&Vb[vrow[dt] + kvp];
        }

        // QK(t) from Ks[p] (swapped): s0 = kv 0..15, s1 = kv 16..31
        f32x4 s0 = {}, s1 = {};
        #pragma unroll
        for (int c = 0; c < 8; ++c) {
            short8 kb0 = *(const short8*)&Ks[p][lr][c * 32 + lg * 8];
            short8 kb1 = *(const short8*)&Ks[p][16 + lr][c * 32 + lg * 8];
            s0 = __builtin_amdgcn_mfma_f32_16x16x32_bf16(kb0, aq[c], s0, 0, 0, 0);
            s1 = __builtin_amdgcn_mfma_f32_16x16x32_bf16(kb1, aq[c], s1, 0, 0, 0);
        }

        // write staged K(t+1) into the other buffer (conflict-free map)
        if (have) {
            *(int4*)&Ks[p ^ 1][krow][kc8]       = x0;
            *(int4*)&Ks[p ^ 1][krow][kc8 + 64]  = x1;
            *(int4*)&Ks[p ^ 1][krow][kc8 + 128] = x2;
            *(int4*)&Ks[p ^ 1][krow][kc8 + 192] = x3;
        }

        // online softmax for q=lr (log2 domain), defer-rescale THR=11
        float mx = fmaxf(fmaxf(fmaxf(s0[0], s0[1]), fmaxf(s0[2], s0[3])),
                         fmaxf(fmaxf(s1[0], s1[1]), fmaxf(s1[2], s1[3])));
        mx = fmaxf(mx, __shfl_xor(mx, 16, 64));
        mx = fmaxf(mx, __shfl_xor(mx, 32, 64));

        const int need = __any(mx > m_run + 11.0f);
        if (need) {
            float mnew = fmaxf(m_run, mx);
            float corr = exp2f(m_run - mnew);
            m_run = mnew;
            if (lane < 16) Cor[p ^ 1][wv][lr] = corr;
        }
        if (lane == 0) Flg[p ^ 1][wv] = need;

        float p0[4], p1[4];
        #pragma unroll
        for (int r = 0; r < 4; ++r) {
            p0[r] = exp2f(s0[r] - m_run);
            p1[r] = exp2f(s1[r] - m_run);
        }

        {   // pack P -> Ps[p^1] (kv-contiguous per lane), 2x b64
            unsigned int w0 = (unsigned)f2bf(p0[0]) | ((unsigned)f2bf(p0[1]) << 16);
            unsigned int w1 = (unsigned)f2bf(p0[2]) | ((unsigned)f2bf(p0[3]) << 16);
            unsigned int w2 = (unsigned)f2bf(p1[0]) | ((unsigned)f2bf(p1[1]) << 16);
            unsigned int w3 = (unsigned)f2bf(p1[2]) | ((unsigned)f2bf(p1[3]) << 16);
            *(unsigned long long*)&Ps[p ^ 1][wv][lr][4 * lg] =
                (unsigned long long)w0 | ((unsigned long long)w1 << 32);
            *(unsigned long long*)&Ps[p ^ 1][wv][lr][16 + 4 * lg] =
                (unsigned long long)w2 | ((unsigned long long)w3 << 32);
        }

        // PV(t-1): P from Ps[p], rescale via Flg/Cor[p], V frags from global.
        // l accumulates via the ones-column MFMA (same Cor rescale as o).
        if (t > 0) {
            short8 pa[4];
            #pragma unroll
            for (int qt = 0; qt < 4; ++qt)
                pa[qt] = *(const short8*)&Ps[p][qt][lr][lg * 8];
            #pragma unroll
            for (int qt = 0; qt < 4; ++qt) {
                if (Flg[p][qt]) {
                    float4 c4 = *(const float4*)&Cor[p][qt][lg * 4];
                    #pragma unroll
                    for (int dt = 0; dt < 4; ++dt) {
                        o[qt][dt][0] *= c4.x; o[qt][dt][1] *= c4.y;
                        o[qt][dt][2] *= c4.z; o[qt][dt][3] *= c4.w;
                    }
                    o_l[qt][0] *= c4.x; o_l[qt][1] *= c4.y;
                    o_l[qt][2] *= c4.z; o_l[qt][3] *= c4.w;
                }
                #pragma unroll
                for (int dt = 0; dt < 4; ++dt)
                    o[qt][dt] = __builtin_amdgcn_mfma_f32_16x16x32_bf16(pa[qt], vbr[dt], o[qt][dt], 0, 0, 0);
                o_l[qt] = __builtin_amdgcn_mfma_f32_16x16x32_bf16(pa[qt], vone, o_l[qt], 0, 0, 0);
            }
        }
        __syncthreads();   // Ks[p^1] + Ps/Cor/Flg[p^1] visible; reads of [p] done
    }

    // epilogue: PV(NT-1) from Ps[NT&1]
    {
        const int p = NT & 1;
        const size_t kvp = (size_t)(NT - 1) * 32 + lg * 8;
        short8 vbr[4];
        #pragma unroll
        for (int dt = 0; dt < 4; ++dt)
            vbr[dt] = *(const short8*)&Vb[vrow[dt] + kvp];
        short8 pa[4];
        #pragma unroll
        for (int qt = 0; qt < 4; ++qt)
            pa[qt] = *(const short8*)&Ps[p][qt][lr][lg * 8];
        #pragma unroll
        for (int qt = 0; qt < 4; ++qt) {
            if (Flg[p][qt]) {
                float4 c4 = *(const float4*)&Cor[p][qt][lg * 4];
                #pragma unroll
                for (int dt = 0; dt < 4; ++dt) {
                    o[qt][dt][0] *= c4.x; o[qt][dt][1] *= c4.y;
                    o[qt][dt][2] *= c4.z; o[qt][dt][3] *= c4.w;
                }
                o_l[qt][0] *= c4.x; o_l[qt][1] *= c4.y;
                o_l[qt][2] *= c4.z; o_l[qt][3] *= c4.w;
            }
            #pragma unroll
            for (int dt = 0; dt < 4; ++dt)
                o[qt][dt] = __builtin_amdgcn_mfma_f32_16x16x32_bf16(pa[qt], vbr[dt], o[qt][dt], 0, 0, 0);
            o_l[qt] = __builtin_amdgcn_mfma_f32_16x16x32_bf16(pa[qt], vone, o_l[qt], 0, 0, 0);
        }
    }

    // normalize with the MFMA-accumulated l (already in o's lane mapping)
    #pragma unroll
    for (int qt = 0; qt < 4; ++qt) {
        float inv[4] = {1.f / o_l[qt][0], 1.f / o_l[qt][1],
                        1.f / o_l[qt][2], 1.f / o_l[qt][3]};
        #pragma unroll
        for (int dt = 0; dt < 4; ++dt)
            #pragma unroll
            for (int r = 0; r < 4; ++r)
                A[(qblk + qt * 16 + lg * 4 + r) * 256 + wv * 64 + dt * 16 + lr] =
                    f2bf(o[qt][dt][r] * inv[r]);
    }
}

extern "C" void kernel_launch(void* const* d_in, const int* in_sizes, int n_in,
                              void* d_out, int out_size, void* d_ws, size_t ws_size,
                              hipStream_t stream) {
    (void)in_sizes; (void)n_in; (void)out_size; (void)ws_size;
    const float* x  = (const float*)d_in[0];
    const float* Wq = (const float*)d_in[1];
    const float* bq = (const float*)d_in[2];
    const float* Wk = (const float*)d_in[3];
    const float* bk = (const float*)d_in[4];
    const float* Wv = (const float*)d_in[5];
    const float* bv = (const float*)d_in[6];
    const float* Wo = (const float*)d_in[7];
    const float* bo = (const float*)d_in[8];
    float* out = (float*)d_out;

    char* ws = (char*)d_ws;
    const size_t MB16 = (size_t)16 * 1024 * 1024;
    unsigned short* qb = (unsigned short*)(ws);
    unsigned short* kb = (unsigned short*)(ws + MB16);
    unsigned short* vt = (unsigned short*)(ws + 2 * MB16);  // V^T [b][d][S]
    unsigned short* ab = (unsigned short*)(ws + 3 * MB16);

    dim3 gg(256, 2), bb(256);
    // scores in log2 domain: Q scale = d^-0.5 * log2(e)
    proj_gemm<false, 0><<<gg, bb, 0, stream>>>(x, Wq, bq, qb, 0.0625f * 1.44269504f);
    proj_gemm<false, 0><<<gg, bb, 0, stream>>>(x, Wk, bk, kb, 1.0f);
    proj_gemm<false, 2><<<gg, bb, 0, stream>>>(x, Wv, bv, vt, 1.0f);
    attn_kernel<<<dim3(512), bb, 0, stream>>>(qb, kb, vt, ab);
    proj_gemm<true, 1><<<gg, bb, 0, stream>>>(ab, Wo, bo, out, 1.0f);
}